// Round 1
// baseline (130.367 us; speedup 1.0000x reference)
//
#include <hip/hip_runtime.h>
#include <hip/hip_bf16.h>

// One-hot: label (H*W int32) -> out (N, H, W) float32.
// Memory-bound: 64 MiB read + 512 MiB write. Each thread loads 4 labels
// (int4, 16B coalesced) and stores one float4 per class plane.
__global__ void __launch_bounds__(256) get_one_hot_59442347376951_kernel(
    const int* __restrict__ label, float* __restrict__ out,
    int total /* H*W */, int N) {
    long long i = ((long long)blockIdx.x * blockDim.x + threadIdx.x) * 4;
    if (i >= total) return;

    int4 lab = *reinterpret_cast<const int4*>(label + i);

    for (int n = 0; n < N; ++n) {
        float4 v;
        v.x = (lab.x == n) ? 1.0f : 0.0f;
        v.y = (lab.y == n) ? 1.0f : 0.0f;
        v.z = (lab.z == n) ? 1.0f : 0.0f;
        v.w = (lab.w == n) ? 1.0f : 0.0f;
        *reinterpret_cast<float4*>(out + (long long)n * total + i) = v;
    }
}

extern "C" void kernel_launch(void* const* d_in, const int* in_sizes, int n_in,
                              void* d_out, int out_size, void* d_ws, size_t ws_size,
                              hipStream_t stream) {
    const int* label = (const int*)d_in[0];
    float* out = (float*)d_out;

    int total = in_sizes[0];          // H*W = 16,777,216
    int N = out_size / total;         // 8

    int threads = total / 4;          // total divisible by 4
    int block = 256;
    int grid = (threads + block - 1) / block;

    get_one_hot_59442347376951_kernel<<<grid, block, 0, stream>>>(label, out, total, N);
}